// Round 1
// baseline (604.333 us; speedup 1.0000x reference)
//
#include <hip/hip_runtime.h>
#include <stdint.h>

// Problem constants
#define BB 256
#define NNODE 12
#define PP 66
#define DNF 1024
#define DEF 1024
#define DD 512
#define MROWS (BB*PP)        // 16896
#define MNODE (BB*NNODE)     // 3072

typedef __attribute__((ext_vector_type(8))) short s16x8;
typedef __attribute__((ext_vector_type(4))) float f32x4;

__device__ __forceinline__ unsigned short f2bf(float f) {
  union { float f; unsigned u; } v; v.f = f;
  return (unsigned short)((v.u + 0x7FFFu + ((v.u >> 16) & 1u)) >> 16);
}
__device__ __forceinline__ float bf2f(unsigned short h) {
  union { unsigned u; float f; } v; v.u = ((unsigned)h) << 16;
  return v.f;
}

__device__ __forceinline__ void gll16(const void* g, void* l) {
  __builtin_amdgcn_global_load_lds(
      (const __attribute__((address_space(1))) void*)g,
      (__attribute__((address_space(3))) void*)l, 16, 0, 0);
}

// ---------------- prep kernels ----------------

// fp32 -> bf16 (vectorized), n4 = elements/4
__global__ __launch_bounds__(256) void k_conv_bf16(const float* __restrict__ src,
                                                   unsigned short* __restrict__ dst, int n4) {
  int i = blockIdx.x * 256 + threadIdx.x;
  if (i < n4) {
    float4 v = ((const float4*)src)[i];
    ushort4 o;
    o.x = f2bf(v.x); o.y = f2bf(v.y); o.z = f2bf(v.z); o.w = f2bf(v.w);
    ((ushort4*)dst)[i] = o;
  }
}

// W [K][N] fp32 -> WT [N][K] bf16 ; K,N multiples of 32
__global__ __launch_bounds__(256) void k_transpose_bf(const float* __restrict__ W,
                                                      unsigned short* __restrict__ WT,
                                                      int K, int N) {
  __shared__ float tile[32][33];
  int kt = blockIdx.x * 32, nt = blockIdx.y * 32;
  int tx = threadIdx.x & 31, ty = threadIdx.x >> 5;  // ty 0..7
#pragma unroll
  for (int i = 0; i < 32; i += 8)
    tile[ty + i][tx] = W[(size_t)(kt + ty + i) * N + nt + tx];
  __syncthreads();
#pragma unroll
  for (int i = 0; i < 32; i += 8)
    WT[(size_t)(nt + ty + i) * K + kt + tx] = f2bf(tile[tx][ty + i]);
}

// gather + average edge features / embeddings per pair-row
__global__ __launch_bounds__(256) void k_gather_ef(const float* __restrict__ EF,
                                                   const float* __restrict__ EE,
                                                   const int* __restrict__ pairs,
                                                   unsigned short* __restrict__ efm,
                                                   unsigned short* __restrict__ emb) {
  int r = blockIdx.x;                 // 0..16895
  int b = r / PP;
  int i0 = pairs[r * 2 + 0], i1 = pairs[r * 2 + 1];
  int t = threadIdx.x;
  // edge_features: rows of 1024 fp32
  const float4* e01 = (const float4*)(EF + ((size_t)((b * NNODE + i0) * NNODE + i1)) * DEF);
  const float4* e10 = (const float4*)(EF + ((size_t)((b * NNODE + i1) * NNODE + i0)) * DEF);
  float4 a = e01[t], c = e10[t];
  ushort4 o;
  o.x = f2bf(0.5f * (a.x + c.x));
  o.y = f2bf(0.5f * (a.y + c.y));
  o.z = f2bf(0.5f * (a.z + c.z));
  o.w = f2bf(0.5f * (a.w + c.w));
  ((ushort4*)(efm + (size_t)r * DEF))[t] = o;
  // edge_embeddings: rows of 512 fp32 ; store 0.25*(ee01+ee10)
  const float2* g01 = (const float2*)(EE + ((size_t)((b * NNODE + i0) * NNODE + i1)) * DD);
  const float2* g10 = (const float2*)(EE + ((size_t)((b * NNODE + i1) * NNODE + i0)) * DD);
  float2 x = g01[t], y = g10[t];
  ushort2 eo;
  eo.x = f2bf(0.25f * (x.x + y.x));
  eo.y = f2bf(0.25f * (x.y + y.y));
  ((ushort2*)(emb + (size_t)r * DD))[t] = eo;
}

// scatter nf rows into ci columns [0,1024), zero for invalid rows
__global__ __launch_bounds__(256) void k_gather_ci(const unsigned short* __restrict__ nf,
                                                   const int* __restrict__ pairs,
                                                   const int* __restrict__ nrels,
                                                   unsigned short* __restrict__ ci) {
  int r = blockIdx.x;
  int b = r / PP, p = r - b * PP;
  bool valid = p < nrels[b];
  int i0 = pairs[r * 2 + 0], i1 = pairs[r * 2 + 1];
  int t = threadIdx.x;
  int col = t * 4;
  ushort4 v = make_ushort4(0, 0, 0, 0);
  if (valid) {
    const unsigned short* src = (col < 512)
        ? nf + ((size_t)(b * NNODE + i0)) * DD + col
        : nf + ((size_t)(b * NNODE + i1)) * DD + (col - 512);
    v = *(const ushort4*)src;
  }
  ((ushort4*)(ci + (size_t)r * 1536))[t] = v;
}

// ---------------- MFMA GEMM ----------------
// C = A[M][K](bf16) * BT[N][K]^T(bf16), 128x128 tile, BK=64, 4 waves (2x2),
// global_load_lds staging with pre-swizzled source ((l&7)^(l>>3)) so ds_read_b128
// is bank-conflict-free. EPI: 0 = +bias -> bf16 out ; 1 = e-assembly into ci with
// mask ; 2 = relu(+bias) -> bf16 out.
template <int EPI>
__global__ __launch_bounds__(256) void k_gemm(
    const unsigned short* __restrict__ A,
    const unsigned short* __restrict__ BT,
    int Ntiles, int K,
    const float* __restrict__ bias,
    unsigned short* __restrict__ outb, int ldo,
    const unsigned short* __restrict__ em,
    const int* __restrict__ nrels,
    unsigned short* __restrict__ ci) {
  __shared__ __align__(16) unsigned short sm[16384];  // A: 16KB, B: 16KB
  char* smc = (char*)sm;
  const int t = threadIdx.x;
  const int l = t & 63, w = t >> 6;
  const int wm = w >> 1, wn = w & 1;
  const int bid = blockIdx.x;
  const int tn = bid % Ntiles, tm = bid / Ntiles;

  const int lrow = l >> 3;               // 0..7
  const int scol = (l & 7) ^ lrow;       // pre-swizzled source chunk
  const unsigned short* Ap = A + (size_t)(tm * 128 + w * 8 + lrow) * K + scol * 8;
  const unsigned short* Bp = BT + (size_t)(tn * 128 + w * 8 + lrow) * K + scol * 8;

  f32x4 acc[4][4] = {};

  const int hi = l >> 4, l15 = l & 15, l7 = l & 7;
  const int nk = K >> 6;

  for (int kt = 0; kt < nk; ++kt) {
#pragma unroll
    for (int c = 0; c < 4; ++c) {
      gll16(Ap + (size_t)c * 32 * K, smc + c * 4096 + w * 1024);
      gll16(Bp + (size_t)c * 32 * K, smc + 16384 + c * 4096 + w * 1024);
    }
    __syncthreads();  // drains vmcnt(0): LDS tiles ready
#pragma unroll
    for (int kk = 0; kk < 2; ++kk) {
      const int cb = (((kk << 2) + hi) ^ l7) << 4;
      s16x8 af[4], bfr[4];
#pragma unroll
      for (int m = 0; m < 4; m++)
        af[m] = *(const s16x8*)(smc + (wm * 64 + m * 16 + l15) * 128 + cb);
#pragma unroll
      for (int n = 0; n < 4; n++)
        bfr[n] = *(const s16x8*)(smc + 16384 + (wn * 64 + n * 16 + l15) * 128 + cb);
#pragma unroll
      for (int m = 0; m < 4; m++)
#pragma unroll
        for (int n = 0; n < 4; n++)
          asm volatile("v_mfma_f32_16x16x32_bf16 %0, %1, %2, %0"
                       : "+v"(acc[m][n])
                       : "v"(af[m]), "v"(bfr[n]));
    }
    __syncthreads();  // all waves done reading before next stage
    Ap += 64;
    Bp += 64;
  }
  asm volatile("s_nop 7\n\ts_nop 7\n\ts_nop 7" :::);  // MFMA->VALU hazard guard

  // C/D layout: col = lane&15, row = (lane>>4)*4 + reg
  const int gr_base = tm * 128 + wm * 64 + (hi << 2);
  const int gc_base = tn * 128 + wn * 64 + l15;
#pragma unroll
  for (int n = 0; n < 4; n++) {
    const int gc = gc_base + n * 16;
    const float bv = bias[gc];
#pragma unroll
    for (int m = 0; m < 4; m++) {
#pragma unroll
      for (int i = 0; i < 4; i++) {
        const int gr = gr_base + m * 16 + i;
        float v = acc[m][n][i] + bv;
        if constexpr (EPI == 0) {
          outb[(size_t)gr * ldo + gc] = f2bf(v);
        } else if constexpr (EPI == 1) {
          int b = gr / PP, p = gr - b * PP;
          float e = bf2f(em[(size_t)gr * DD + gc]) + 0.5f * v;
          ci[(size_t)gr * 1536 + 1024 + gc] =
              (p < nrels[b]) ? f2bf(e) : (unsigned short)0;
        } else {
          outb[(size_t)gr * ldo + gc] = f2bf(v > 0.f ? v : 0.f);
        }
      }
    }
  }
}

// ---------------- layer-2 heads ----------------
// one block per row; wave 0/1/2 -> lr/cr/mr. K=512 dot per class, butterfly reduce.
__global__ __launch_bounds__(192) void k_head_out(
    const unsigned short* __restrict__ h1,  // [3][16896][512] bf16
    const float* __restrict__ w2_lr, const float* __restrict__ b2_lr,
    const float* __restrict__ w2_cr, const float* __restrict__ b2_cr,
    const float* __restrict__ w2_mr, const float* __restrict__ b2_mr,
    float* __restrict__ out) {
  int r = blockIdx.x;
  int w = threadIdx.x >> 6, l = threadIdx.x & 63;
  const float* W2;
  const float* b2;
  int C;
  size_t obase;
  if (w == 0) { W2 = w2_lr; b2 = b2_lr; C = 9; obase = 0; }
  else if (w == 1) { W2 = w2_cr; b2 = b2_cr; C = 3; obase = (size_t)MROWS * 9; }
  else { W2 = w2_mr; b2 = b2_mr; C = 5; obase = (size_t)MROWS * 12; }

  const unsigned short* x = h1 + ((size_t)w * MROWS + r) * DD + l * 8;
  ushort4 xa = *(const ushort4*)x;
  ushort4 xb = *(const ushort4*)(x + 4);
  float xv[8];
  xv[0] = bf2f(xa.x); xv[1] = bf2f(xa.y); xv[2] = bf2f(xa.z); xv[3] = bf2f(xa.w);
  xv[4] = bf2f(xb.x); xv[5] = bf2f(xb.y); xv[6] = bf2f(xb.z); xv[7] = bf2f(xb.w);

  float acc[9] = {0.f, 0.f, 0.f, 0.f, 0.f, 0.f, 0.f, 0.f, 0.f};
#pragma unroll
  for (int j = 0; j < 8; j++) {
    int k = l * 8 + j;
    const float* wrow = W2 + (size_t)k * C;
#pragma unroll
    for (int c = 0; c < 9; c++)
      if (c < C) acc[c] += xv[j] * wrow[c];
  }
#pragma unroll
  for (int c = 0; c < 9; c++) {
#pragma unroll
    for (int off = 32; off; off >>= 1) acc[c] += __shfl_xor(acc[c], off);
  }
  float res = 0.f;
#pragma unroll
  for (int c = 0; c < 9; c++)
    if (l == c) res = acc[c];
  if (l < C) out[obase + (size_t)r * C + l] = res + b2[l];
}

// ---------------- launcher ----------------
extern "C" void kernel_launch(void* const* d_in, const int* in_sizes, int n_in,
                              void* d_out, int out_size, void* d_ws, size_t ws_size,
                              hipStream_t stream) {
  const float* node   = (const float*)d_in[0];
  const float* EF     = (const float*)d_in[1];
  const float* EE     = (const float*)d_in[2];
  const int*   pairs  = (const int*)d_in[3];
  const int*   nrels  = (const int*)d_in[4];
  const float* W_node = (const float*)d_in[5];
  const float* b_node = (const float*)d_in[6];
  const float* W_edge = (const float*)d_in[7];
  const float* b_edge = (const float*)d_in[8];
  const float* hW0[3] = {(const float*)d_in[9],  (const float*)d_in[15], (const float*)d_in[21]};
  const float* hb0[3] = {(const float*)d_in[10], (const float*)d_in[16], (const float*)d_in[22]};
  const float* hW1[3] = {(const float*)d_in[11], (const float*)d_in[17], (const float*)d_in[23]};
  const float* hb1[3] = {(const float*)d_in[12], (const float*)d_in[18], (const float*)d_in[24]};
  const float* hW2[3] = {(const float*)d_in[13], (const float*)d_in[19], (const float*)d_in[25]};
  const float* hb2[3] = {(const float*)d_in[14], (const float*)d_in[20], (const float*)d_in[26]};

  char* ws = (char*)d_ws;
  size_t off = 0;
  auto alloc = [&](size_t bytes) {
    char* p = ws + off;
    off += (bytes + 255) & ~(size_t)255;
    return p;
  };
  unsigned short* WnT     = (unsigned short*)alloc((size_t)512 * 1024 * 2);
  unsigned short* WeT     = (unsigned short*)alloc((size_t)512 * 1024 * 2);
  unsigned short* W0T     = (unsigned short*)alloc((size_t)3072 * 1536 * 2);
  unsigned short* W1T     = (unsigned short*)alloc((size_t)3 * 512 * 1024 * 2);
  unsigned short* node_bf = (unsigned short*)alloc((size_t)MNODE * DNF * 2);
  unsigned short* nf      = (unsigned short*)alloc((size_t)MNODE * DD * 2);
  unsigned short* efm     = (unsigned short*)alloc((size_t)MROWS * DEF * 2);  // reused as h0
  unsigned short* EMb     = (unsigned short*)alloc((size_t)MROWS * DD * 2);
  unsigned short* ci      = (unsigned short*)alloc((size_t)MROWS * 1536 * 2);
  unsigned short* h1      = (unsigned short*)alloc((size_t)3 * MROWS * DD * 2);
  unsigned short* h0 = efm;  // overlay: efm dead before h0 is written

  // prep
  k_conv_bf16<<<MNODE, 256, 0, stream>>>(node, node_bf, MNODE * DNF / 4);
  k_transpose_bf<<<dim3(1024 / 32, 512 / 32), 256, 0, stream>>>(W_node, WnT, 1024, 512);
  k_transpose_bf<<<dim3(1024 / 32, 512 / 32), 256, 0, stream>>>(W_edge, WeT, 1024, 512);
  for (int h = 0; h < 3; h++) {
    k_transpose_bf<<<dim3(1536 / 32, 1024 / 32), 256, 0, stream>>>(
        hW0[h], W0T + (size_t)h * 1024 * 1536, 1536, 1024);
    k_transpose_bf<<<dim3(1024 / 32, 512 / 32), 256, 0, stream>>>(
        hW1[h], W1T + (size_t)h * 512 * 1024, 1024, 512);
  }
  k_gather_ef<<<MROWS, 256, 0, stream>>>(EF, EE, pairs, efm, EMb);

  // nf = node_bf @ WnT^T + b_node   (M=3072, N=512, K=1024)
  k_gemm<0><<<(MNODE / 128) * (512 / 128), 256, 0, stream>>>(
      node_bf, WnT, 512 / 128, 1024, b_node, nf, 512, nullptr, nullptr, nullptr);
  // ci[:, :1024] = gathered nf (masked)
  k_gather_ci<<<MROWS, 256, 0, stream>>>(nf, pairs, nrels, ci);
  // ci[:, 1024:1536] = e = 0.25*(ee+ee') + 0.5*(efm@We + b_edge)  (masked)
  k_gemm<1><<<(MROWS / 128) * (512 / 128), 256, 0, stream>>>(
      efm, WeT, 512 / 128, 1024, b_edge, nullptr, 0, EMb, nrels, ci);

  // heads: layer0 (K=1536,N=1024) -> h0 ; layer1 (K=1024,N=512) -> h1[h]
  for (int h = 0; h < 3; h++) {
    k_gemm<2><<<(MROWS / 128) * (1024 / 128), 256, 0, stream>>>(
        ci, W0T + (size_t)h * 1024 * 1536, 1024 / 128, 1536, hb0[h],
        h0, 1024, nullptr, nullptr, nullptr);
    k_gemm<2><<<(MROWS / 128) * (512 / 128), 256, 0, stream>>>(
        h0, W1T + (size_t)h * 512 * 1024, 512 / 128, 1024, hb1[h],
        h1 + (size_t)h * MROWS * DD, 512, nullptr, nullptr, nullptr);
  }

  // layer2 -> d_out (fp32): lr | cr | mr
  k_head_out<<<MROWS, 192, 0, stream>>>(h1, hW2[0], hb2[0], hW2[1], hb2[1],
                                        hW2[2], hb2[2], (float*)d_out);
}

// Round 2
// 484.592 us; speedup vs baseline: 1.2471x; 1.2471x over previous
//
#include <hip/hip_runtime.h>
#include <stdint.h>

// Problem constants
#define BB 256
#define NNODE 12
#define PP 66
#define DNF 1024
#define DEF 1024
#define DD 512
#define MROWS (BB*PP)        // 16896
#define MNODE (BB*NNODE)     // 3072
#define MTILES (MROWS/128)   // 132

typedef __attribute__((ext_vector_type(8))) short s16x8;
typedef __attribute__((ext_vector_type(4))) float f32x4;

__device__ __forceinline__ unsigned short f2bf(float f) {
  union { float f; unsigned u; } v; v.f = f;
  return (unsigned short)((v.u + 0x7FFFu + ((v.u >> 16) & 1u)) >> 16);
}
__device__ __forceinline__ float bf2f(unsigned short h) {
  union { unsigned u; float f; } v; v.u = ((unsigned)h) << 16;
  return v.f;
}

__device__ __forceinline__ void gll16(const void* g, void* l) {
  __builtin_amdgcn_global_load_lds(
      (const __attribute__((address_space(1))) void*)g,
      (__attribute__((address_space(3))) void*)l, 16, 0, 0);
}

// ---------------- prep kernels ----------------

// fp32 -> bf16 (vectorized), n4 = elements/4
__global__ __launch_bounds__(256) void k_conv_bf16(const float* __restrict__ src,
                                                   unsigned short* __restrict__ dst, int n4) {
  int i = blockIdx.x * 256 + threadIdx.x;
  if (i < n4) {
    float4 v = ((const float4*)src)[i];
    ushort4 o;
    o.x = f2bf(v.x); o.y = f2bf(v.y); o.z = f2bf(v.z); o.w = f2bf(v.w);
    ((ushort4*)dst)[i] = o;
  }
}

// W [K][N] fp32 -> WT [N][K] bf16 ; K,N multiples of 32
__global__ __launch_bounds__(256) void k_transpose_bf(const float* __restrict__ W,
                                                      unsigned short* __restrict__ WT,
                                                      int K, int N) {
  __shared__ float tile[32][33];
  int kt = blockIdx.x * 32, nt = blockIdx.y * 32;
  int tx = threadIdx.x & 31, ty = threadIdx.x >> 5;  // ty 0..7
#pragma unroll
  for (int i = 0; i < 32; i += 8)
    tile[ty + i][tx] = W[(size_t)(kt + ty + i) * N + nt + tx];
  __syncthreads();
#pragma unroll
  for (int i = 0; i < 32; i += 8)
    WT[(size_t)(nt + ty + i) * K + kt + tx] = f2bf(tile[tx][ty + i]);
}

// layer-2 weight prep: W2 [512][C] fp32 -> W2T [128][512] bf16, rows >= C zero.
// Also packs padded bias b2pad [3][128].
__global__ __launch_bounds__(256) void k_prep_w2(
    const float* __restrict__ w2_lr, const float* __restrict__ w2_cr,
    const float* __restrict__ w2_mr,
    const float* __restrict__ b2_lr, const float* __restrict__ b2_cr,
    const float* __restrict__ b2_mr,
    unsigned short* __restrict__ W2T, float* __restrict__ b2pad) {
  const int h = blockIdx.y;
  const int C = (h == 0) ? 9 : ((h == 1) ? 3 : 5);
  const float* W2 = (h == 0) ? w2_lr : ((h == 1) ? w2_cr : w2_mr);
  const float* b2 = (h == 0) ? b2_lr : ((h == 1) ? b2_cr : b2_mr);
  int e = blockIdx.x * 256 + threadIdx.x;   // 0..65535
  int n = e >> 9, k = e & 511;
  W2T[(size_t)h * 65536 + e] = (n < C) ? f2bf(W2[(size_t)k * C + n]) : (unsigned short)0;
  if (blockIdx.x == 0 && threadIdx.x < 128)
    b2pad[h * 128 + threadIdx.x] = (threadIdx.x < C) ? b2[threadIdx.x] : 0.f;
}

// gather + average edge features / embeddings per pair-row
__global__ __launch_bounds__(256) void k_gather_ef(const float* __restrict__ EF,
                                                   const float* __restrict__ EE,
                                                   const int* __restrict__ pairs,
                                                   unsigned short* __restrict__ efm,
                                                   unsigned short* __restrict__ emb) {
  int r = blockIdx.x;                 // 0..16895
  int b = r / PP;
  int i0 = pairs[r * 2 + 0], i1 = pairs[r * 2 + 1];
  int t = threadIdx.x;
  // edge_features: rows of 1024 fp32
  const float4* e01 = (const float4*)(EF + ((size_t)((b * NNODE + i0) * NNODE + i1)) * DEF);
  const float4* e10 = (const float4*)(EF + ((size_t)((b * NNODE + i1) * NNODE + i0)) * DEF);
  float4 a = e01[t], c = e10[t];
  ushort4 o;
  o.x = f2bf(0.5f * (a.x + c.x));
  o.y = f2bf(0.5f * (a.y + c.y));
  o.z = f2bf(0.5f * (a.z + c.z));
  o.w = f2bf(0.5f * (a.w + c.w));
  ((ushort4*)(efm + (size_t)r * DEF))[t] = o;
  // edge_embeddings: rows of 512 fp32 ; store 0.25*(ee01+ee10)
  const float2* g01 = (const float2*)(EE + ((size_t)((b * NNODE + i0) * NNODE + i1)) * DD);
  const float2* g10 = (const float2*)(EE + ((size_t)((b * NNODE + i1) * NNODE + i0)) * DD);
  float2 x = g01[t], y = g10[t];
  ushort2 eo;
  eo.x = f2bf(0.25f * (x.x + y.x));
  eo.y = f2bf(0.25f * (x.y + y.y));
  ((ushort2*)(emb + (size_t)r * DD))[t] = eo;
}

// scatter nf rows into ci columns [0,1024), zero for invalid rows
__global__ __launch_bounds__(256) void k_gather_ci(const unsigned short* __restrict__ nf,
                                                   const int* __restrict__ pairs,
                                                   const int* __restrict__ nrels,
                                                   unsigned short* __restrict__ ci) {
  int r = blockIdx.x;
  int b = r / PP, p = r - b * PP;
  bool valid = p < nrels[b];
  int i0 = pairs[r * 2 + 0], i1 = pairs[r * 2 + 1];
  int t = threadIdx.x;
  int col = t * 4;
  ushort4 v = make_ushort4(0, 0, 0, 0);
  if (valid) {
    const unsigned short* src = (col < 512)
        ? nf + ((size_t)(b * NNODE + i0)) * DD + col
        : nf + ((size_t)(b * NNODE + i1)) * DD + (col - 512);
    v = *(const ushort4*)src;
  }
  ((ushort4*)(ci + (size_t)r * 1536))[t] = v;
}

// ---------------- MFMA GEMM ----------------
// C = A[M][K](bf16) * BT[N][K]^T(bf16), 128x128 tile, BK=64, 4 waves (2x2),
// global_load_lds staging with pre-swizzled source ((l&7)^(l>>3)) so ds_read_b128
// is bank-conflict-free. EPI:
//   0 = +bias -> bf16 out
//   1 = e-assembly into ci with mask
//   2 = relu(+bias) -> bf16 out
//   3 = layer-2 heads: tm encodes (head, tile); fp32 out, cols < C only
template <int EPI>
__global__ __launch_bounds__(256) void k_gemm(
    const unsigned short* __restrict__ A,
    const unsigned short* __restrict__ BT,
    int Ntiles, int K,
    const float* __restrict__ bias,
    unsigned short* __restrict__ outb, int ldo,
    const unsigned short* __restrict__ em,
    const int* __restrict__ nrels,
    unsigned short* __restrict__ ci) {
  __shared__ __align__(16) unsigned short sm[16384];  // A: 16KB, B: 16KB
  char* smc = (char*)sm;
  const int t = threadIdx.x;
  const int l = t & 63, w = t >> 6;
  const int wm = w >> 1, wn = w & 1;
  const int bid = blockIdx.x;
  int tn = bid % Ntiles, tm = bid / Ntiles;

  int head = 0;
  if constexpr (EPI == 3) {
    head = tm / MTILES;
    tm = tm - head * MTILES;
    A += (size_t)head * MROWS * DD;       // h1[head]
    BT += (size_t)head * 128 * DD;        // W2T[head]
    bias += head * 128;                   // padded bias
  }

  const int lrow = l >> 3;               // 0..7
  const int scol = (l & 7) ^ lrow;       // pre-swizzled source chunk
  const unsigned short* Ap = A + (size_t)(tm * 128 + w * 8 + lrow) * K + scol * 8;
  const unsigned short* Bp = BT + (size_t)(tn * 128 + w * 8 + lrow) * K + scol * 8;

  f32x4 acc[4][4] = {};

  const int hi = l >> 4, l15 = l & 15, l7 = l & 7;
  const int nk = K >> 6;

  for (int kt = 0; kt < nk; ++kt) {
#pragma unroll
    for (int c = 0; c < 4; ++c) {
      gll16(Ap + (size_t)c * 32 * K, smc + c * 4096 + w * 1024);
      gll16(Bp + (size_t)c * 32 * K, smc + 16384 + c * 4096 + w * 1024);
    }
    __syncthreads();  // drains vmcnt(0): LDS tiles ready
#pragma unroll
    for (int kk = 0; kk < 2; ++kk) {
      const int cb = (((kk << 2) + hi) ^ l7) << 4;
      s16x8 af[4], bfr[4];
#pragma unroll
      for (int m = 0; m < 4; m++)
        af[m] = *(const s16x8*)(smc + (wm * 64 + m * 16 + l15) * 128 + cb);
#pragma unroll
      for (int n = 0; n < 4; n++)
        bfr[n] = *(const s16x8*)(smc + 16384 + (wn * 64 + n * 16 + l15) * 128 + cb);
#pragma unroll
      for (int m = 0; m < 4; m++)
#pragma unroll
        for (int n = 0; n < 4; n++)
          asm volatile("v_mfma_f32_16x16x32_bf16 %0, %1, %2, %0"
                       : "+v"(acc[m][n])
                       : "v"(af[m]), "v"(bfr[n]));
    }
    __syncthreads();  // all waves done reading before next stage
    Ap += 64;
    Bp += 64;
  }
  asm volatile("s_nop 7\n\ts_nop 7\n\ts_nop 7" :::);  // MFMA->VALU hazard guard

  // C/D layout: col = lane&15, row = (lane>>4)*4 + reg
  const int gr_base = tm * 128 + wm * 64 + (hi << 2);
  const int gc_base = tn * 128 + wn * 64 + l15;

  int Cc = 0; size_t obase = 0;
  if constexpr (EPI == 3) {
    Cc = (head == 0) ? 9 : ((head == 1) ? 3 : 5);
    obase = (head == 0) ? 0 : ((head == 1) ? (size_t)MROWS * 9 : (size_t)MROWS * 12);
  }

#pragma unroll
  for (int n = 0; n < 4; n++) {
    const int gc = gc_base + n * 16;
    const float bv = bias[gc];
#pragma unroll
    for (int m = 0; m < 4; m++) {
#pragma unroll
      for (int i = 0; i < 4; i++) {
        const int gr = gr_base + m * 16 + i;
        float v = acc[m][n][i] + bv;
        if constexpr (EPI == 0) {
          outb[(size_t)gr * ldo + gc] = f2bf(v);
        } else if constexpr (EPI == 1) {
          int b = gr / PP, p = gr - b * PP;
          float e = bf2f(em[(size_t)gr * DD + gc]) + 0.5f * v;
          ci[(size_t)gr * 1536 + 1024 + gc] =
              (p < nrels[b]) ? f2bf(e) : (unsigned short)0;
        } else if constexpr (EPI == 2) {
          outb[(size_t)gr * ldo + gc] = f2bf(v > 0.f ? v : 0.f);
        } else {
          if (gc < Cc)
            ((float*)outb)[obase + (size_t)gr * Cc + gc] = v;
        }
      }
    }
  }
}

// ---------------- launcher ----------------
extern "C" void kernel_launch(void* const* d_in, const int* in_sizes, int n_in,
                              void* d_out, int out_size, void* d_ws, size_t ws_size,
                              hipStream_t stream) {
  const float* node   = (const float*)d_in[0];
  const float* EF     = (const float*)d_in[1];
  const float* EE     = (const float*)d_in[2];
  const int*   pairs  = (const int*)d_in[3];
  const int*   nrels  = (const int*)d_in[4];
  const float* W_node = (const float*)d_in[5];
  const float* b_node = (const float*)d_in[6];
  const float* W_edge = (const float*)d_in[7];
  const float* b_edge = (const float*)d_in[8];
  const float* hW0[3] = {(const float*)d_in[9],  (const float*)d_in[15], (const float*)d_in[21]};
  const float* hb0[3] = {(const float*)d_in[10], (const float*)d_in[16], (const float*)d_in[22]};
  const float* hW1[3] = {(const float*)d_in[11], (const float*)d_in[17], (const float*)d_in[23]};
  const float* hb1[3] = {(const float*)d_in[12], (const float*)d_in[18], (const float*)d_in[24]};
  const float* hW2[3] = {(const float*)d_in[13], (const float*)d_in[19], (const float*)d_in[25]};
  const float* hb2[3] = {(const float*)d_in[14], (const float*)d_in[20], (const float*)d_in[26]};

  char* ws = (char*)d_ws;
  size_t off = 0;
  auto alloc = [&](size_t bytes) {
    char* p = ws + off;
    off += (bytes + 255) & ~(size_t)255;
    return p;
  };
  unsigned short* WnT     = (unsigned short*)alloc((size_t)512 * 1024 * 2);
  unsigned short* WeT     = (unsigned short*)alloc((size_t)512 * 1024 * 2);
  unsigned short* W0T     = (unsigned short*)alloc((size_t)3072 * 1536 * 2);
  unsigned short* W1T     = (unsigned short*)alloc((size_t)3 * 512 * 1024 * 2);
  unsigned short* W2T     = (unsigned short*)alloc((size_t)3 * 128 * 512 * 2);
  float*          b2pad   = (float*)alloc((size_t)3 * 128 * 4);
  unsigned short* node_bf = (unsigned short*)alloc((size_t)MNODE * DNF * 2);
  unsigned short* nf      = (unsigned short*)alloc((size_t)MNODE * DD * 2);
  unsigned short* efm     = (unsigned short*)alloc((size_t)MROWS * DEF * 2);  // reused as h0
  unsigned short* EMb     = (unsigned short*)alloc((size_t)MROWS * DD * 2);
  unsigned short* ci      = (unsigned short*)alloc((size_t)MROWS * 1536 * 2);
  unsigned short* h1      = (unsigned short*)alloc((size_t)3 * MROWS * DD * 2);
  unsigned short* h0 = efm;  // overlay: efm dead before h0 is written

  // prep
  k_conv_bf16<<<MNODE, 256, 0, stream>>>(node, node_bf, MNODE * DNF / 4);
  k_transpose_bf<<<dim3(1024 / 32, 512 / 32), 256, 0, stream>>>(W_node, WnT, 1024, 512);
  k_transpose_bf<<<dim3(1024 / 32, 512 / 32), 256, 0, stream>>>(W_edge, WeT, 1024, 512);
  for (int h = 0; h < 3; h++) {
    k_transpose_bf<<<dim3(1536 / 32, 1024 / 32), 256, 0, stream>>>(
        hW0[h], W0T + (size_t)h * 1024 * 1536, 1536, 1024);
    k_transpose_bf<<<dim3(1024 / 32, 512 / 32), 256, 0, stream>>>(
        hW1[h], W1T + (size_t)h * 512 * 1024, 1024, 512);
  }
  k_prep_w2<<<dim3(256, 3), 256, 0, stream>>>(hW2[0], hW2[1], hW2[2],
                                              hb2[0], hb2[1], hb2[2], W2T, b2pad);
  k_gather_ef<<<MROWS, 256, 0, stream>>>(EF, EE, pairs, efm, EMb);

  // nf = node_bf @ WnT^T + b_node   (M=3072, N=512, K=1024)
  k_gemm<0><<<(MNODE / 128) * (512 / 128), 256, 0, stream>>>(
      node_bf, WnT, 512 / 128, 1024, b_node, nf, 512, nullptr, nullptr, nullptr);
  // ci[:, :1024] = gathered nf (masked)
  k_gather_ci<<<MROWS, 256, 0, stream>>>(nf, pairs, nrels, ci);
  // ci[:, 1024:1536] = e = 0.25*(ee+ee') + 0.5*(efm@We + b_edge)  (masked)
  k_gemm<1><<<MTILES * (512 / 128), 256, 0, stream>>>(
      efm, WeT, 512 / 128, 1024, b_edge, nullptr, 0, EMb, nrels, ci);

  // heads: layer0 (K=1536,N=1024) -> h0 ; layer1 (K=1024,N=512) -> h1[h]
  for (int h = 0; h < 3; h++) {
    k_gemm<2><<<MTILES * (1024 / 128), 256, 0, stream>>>(
        ci, W0T + (size_t)h * 1024 * 1536, 1024 / 128, 1536, hb0[h],
        h0, 1024, nullptr, nullptr, nullptr);
    k_gemm<2><<<MTILES * (512 / 128), 256, 0, stream>>>(
        h0, W1T + (size_t)h * 512 * 1024, 512 / 128, 1024, hb1[h],
        h1 + (size_t)h * MROWS * DD, 512, nullptr, nullptr, nullptr);
  }

  // layer2: one merged padded GEMM, all 3 heads -> d_out (fp32) lr | cr | mr
  k_gemm<3><<<3 * MTILES, 256, 0, stream>>>(
      h1, W2T, 1, 512, b2pad, (unsigned short*)d_out, 0,
      nullptr, nullptr, nullptr);
}

// Round 3
// 395.133 us; speedup vs baseline: 1.5294x; 1.2264x over previous
//
#include <hip/hip_runtime.h>
#include <stdint.h>

// Problem constants
#define BB 256
#define NNODE 12
#define PP 66
#define DNF 1024
#define DEF 1024
#define DD 512
#define MROWS (BB*PP)        // 16896
#define MNODE (BB*NNODE)     // 3072
#define MTILES (MROWS/128)   // 132

typedef __attribute__((ext_vector_type(8))) short s16x8;
typedef __attribute__((ext_vector_type(4))) float f32x4;

__device__ __forceinline__ unsigned short f2bf(float f) {
  union { float f; unsigned u; } v; v.f = f;
  return (unsigned short)((v.u + 0x7FFFu + ((v.u >> 16) & 1u)) >> 16);
}
__device__ __forceinline__ float bf2f(unsigned short h) {
  union { unsigned u; float f; } v; v.u = ((unsigned)h) << 16;
  return v.f;
}

__device__ __forceinline__ void gll16(const void* g, void* l) {
  __builtin_amdgcn_global_load_lds(
      (const __attribute__((address_space(1))) void*)g,
      (__attribute__((address_space(3))) void*)l, 16, 0, 0);
}

// bijective XCD-chunk swizzle (m204)
__device__ __forceinline__ int swz_xcd(int orig, int nwg) {
  int q = nwg >> 3, r = nwg & 7, x = orig & 7;
  return (x < r ? x * (q + 1) : r * (q + 1) + (x - r) * q) + (orig >> 3);
}

// ---------------- fused prep kernel ----------------
// segments: [0,3072) conv node->bf16 ; [3072,10240) weight transposes ;
// [10240,11008) W2 pad ; [11008,11020) b0cat ; [11020,11026) b1cat
__global__ __launch_bounds__(256) void k_prep(
    const float* __restrict__ node, unsigned short* __restrict__ node_bf,
    const float* __restrict__ W_node, unsigned short* __restrict__ WnT,
    const float* __restrict__ W_edge, unsigned short* __restrict__ WeT,
    const float* __restrict__ W0a, const float* __restrict__ W0b,
    const float* __restrict__ W0c, unsigned short* __restrict__ W0T,
    const float* __restrict__ W1a, const float* __restrict__ W1b,
    const float* __restrict__ W1c, unsigned short* __restrict__ W1T,
    const float* __restrict__ w2a, const float* __restrict__ w2b,
    const float* __restrict__ w2c,
    const float* __restrict__ b2a, const float* __restrict__ b2b,
    const float* __restrict__ b2c,
    unsigned short* __restrict__ W2T, float* __restrict__ b2pad,
    const float* __restrict__ b0a, const float* __restrict__ b0b,
    const float* __restrict__ b0c, float* __restrict__ b0cat,
    const float* __restrict__ b1a, const float* __restrict__ b1b,
    const float* __restrict__ b1c, float* __restrict__ b1cat) {
  __shared__ float tile[32][33];
  const int bid = blockIdx.x, t = threadIdx.x;
  if (bid < 3072) {
    int i = bid * 256 + t;                 // < 786432
    float4 v = ((const float4*)node)[i];
    ushort4 o;
    o.x = f2bf(v.x); o.y = f2bf(v.y); o.z = f2bf(v.z); o.w = f2bf(v.w);
    ((ushort4*)node_bf)[i] = o;
  } else if (bid < 10240) {
    int tau = bid - 3072;
    const float* src; unsigned short* dst; int K, N;
    if (tau < 512)       { src = W_node; dst = WnT; K = 1024; N = 512; }
    else if (tau < 1024) { src = W_edge; dst = WeT; K = 1024; N = 512; tau -= 512; }
    else if (tau < 5632) {
      int hh = (tau - 1024) / 1536; tau = (tau - 1024) % 1536;
      src = hh == 0 ? W0a : (hh == 1 ? W0b : W0c);
      dst = W0T + (size_t)hh * 1024 * 1536; K = 1536; N = 1024;
    } else {
      int hh = (tau - 5632) / 512; tau = (tau - 5632) % 512;
      src = hh == 0 ? W1a : (hh == 1 ? W1b : W1c);
      dst = W1T + (size_t)hh * 512 * 1024; K = 1024; N = 512;
    }
    int ntiles = N >> 5;
    int kb = (tau / ntiles) * 32, nb = (tau % ntiles) * 32;
    int tx = t & 31, ty = t >> 5;
#pragma unroll
    for (int i = 0; i < 32; i += 8)
      tile[ty + i][tx] = src[(size_t)(kb + ty + i) * N + nb + tx];
    __syncthreads();
#pragma unroll
    for (int i = 0; i < 32; i += 8)
      dst[(size_t)(nb + ty + i) * K + kb + tx] = f2bf(tile[tx][ty + i]);
  } else if (bid < 11008) {
    int e = bid - 10240;
    int h = e >> 8, blk = e & 255;
    const int C = (h == 0) ? 9 : ((h == 1) ? 3 : 5);
    const float* W2 = (h == 0) ? w2a : ((h == 1) ? w2b : w2c);
    const float* b2 = (h == 0) ? b2a : ((h == 1) ? b2b : b2c);
    int idx = blk * 256 + t;               // < 65536
    int n = idx >> 9, k = idx & 511;
    W2T[(size_t)h * 65536 + idx] = (n < C) ? f2bf(W2[(size_t)k * C + n]) : (unsigned short)0;
    if (blk == 0 && t < 128)
      b2pad[h * 128 + t] = (t < C) ? b2[t] : 0.f;
  } else if (bid < 11020) {
    int j = bid - 11008;                   // 0..11
    const float* b0 = (j < 4) ? b0a : (j < 8 ? b0b : b0c);
    b0cat[j * 256 + t] = b0[(j & 3) * 256 + t];
  } else {
    int j = bid - 11020;                   // 0..5
    const float* b1 = (j < 2) ? b1a : (j < 4 ? b1b : b1c);
    b1cat[j * 256 + t] = b1[(j & 1) * 256 + t];
  }
}

// ---------------- gathers (unchanged) ----------------
__global__ __launch_bounds__(256) void k_gather_ef(const float* __restrict__ EF,
                                                   const float* __restrict__ EE,
                                                   const int* __restrict__ pairs,
                                                   unsigned short* __restrict__ efm,
                                                   unsigned short* __restrict__ emb) {
  int r = blockIdx.x;
  int b = r / PP;
  int i0 = pairs[r * 2 + 0], i1 = pairs[r * 2 + 1];
  int t = threadIdx.x;
  const float4* e01 = (const float4*)(EF + ((size_t)((b * NNODE + i0) * NNODE + i1)) * DEF);
  const float4* e10 = (const float4*)(EF + ((size_t)((b * NNODE + i1) * NNODE + i0)) * DEF);
  float4 a = e01[t], c = e10[t];
  ushort4 o;
  o.x = f2bf(0.5f * (a.x + c.x));
  o.y = f2bf(0.5f * (a.y + c.y));
  o.z = f2bf(0.5f * (a.z + c.z));
  o.w = f2bf(0.5f * (a.w + c.w));
  ((ushort4*)(efm + (size_t)r * DEF))[t] = o;
  const float2* g01 = (const float2*)(EE + ((size_t)((b * NNODE + i0) * NNODE + i1)) * DD);
  const float2* g10 = (const float2*)(EE + ((size_t)((b * NNODE + i1) * NNODE + i0)) * DD);
  float2 x = g01[t], y = g10[t];
  ushort2 eo;
  eo.x = f2bf(0.25f * (x.x + y.x));
  eo.y = f2bf(0.25f * (x.y + y.y));
  ((ushort2*)(emb + (size_t)r * DD))[t] = eo;
}

__global__ __launch_bounds__(256) void k_gather_ci(const unsigned short* __restrict__ nf,
                                                   const int* __restrict__ pairs,
                                                   const int* __restrict__ nrels,
                                                   unsigned short* __restrict__ ci) {
  int r = blockIdx.x;
  int b = r / PP, p = r - b * PP;
  bool valid = p < nrels[b];
  int i0 = pairs[r * 2 + 0], i1 = pairs[r * 2 + 1];
  int t = threadIdx.x;
  int col = t * 4;
  ushort4 v = make_ushort4(0, 0, 0, 0);
  if (valid) {
    const unsigned short* src = (col < 512)
        ? nf + ((size_t)(b * NNODE + i0)) * DD + col
        : nf + ((size_t)(b * NNODE + i1)) * DD + (col - 512);
    v = *(const ushort4*)src;
  }
  ((ushort4*)(ci + (size_t)r * 1536))[t] = v;
}

// ---------------- 128-tile MFMA GEMM (small shapes + fallback) ----------------
template <int EPI>
__global__ __launch_bounds__(256) void k_gemm(
    const unsigned short* __restrict__ A,
    const unsigned short* __restrict__ BT,
    int Ntiles, int K,
    const float* __restrict__ bias,
    unsigned short* __restrict__ outb, int ldo,
    const unsigned short* __restrict__ em,
    const int* __restrict__ nrels,
    unsigned short* __restrict__ ci) {
  __shared__ __align__(16) unsigned short sm[16384];
  char* smc = (char*)sm;
  const int t = threadIdx.x;
  const int l = t & 63, w = t >> 6;
  const int wm = w >> 1, wn = w & 1;
  const int bid = blockIdx.x;
  int tn = bid % Ntiles, tm = bid / Ntiles;

  int head = 0;
  if constexpr (EPI == 3) {
    head = tm / MTILES;
    tm = tm - head * MTILES;
    A += (size_t)head * MROWS * DD;
    BT += (size_t)head * 128 * DD;
    bias += head * 128;
  }

  const int lrow = l >> 3;
  const int scol = (l & 7) ^ lrow;
  const unsigned short* Ap = A + (size_t)(tm * 128 + w * 8 + lrow) * K + scol * 8;
  const unsigned short* Bp = BT + (size_t)(tn * 128 + w * 8 + lrow) * K + scol * 8;

  f32x4 acc[4][4] = {};
  const int hi = l >> 4, l15 = l & 15, l7 = l & 7;
  const int nk = K >> 6;

  for (int kt = 0; kt < nk; ++kt) {
#pragma unroll
    for (int c = 0; c < 4; ++c) {
      gll16(Ap + (size_t)c * 32 * K, smc + c * 4096 + w * 1024);
      gll16(Bp + (size_t)c * 32 * K, smc + 16384 + c * 4096 + w * 1024);
    }
    __syncthreads();
#pragma unroll
    for (int kk = 0; kk < 2; ++kk) {
      const int cb = (((kk << 2) + hi) ^ l7) << 4;
      s16x8 af[4], bfr[4];
#pragma unroll
      for (int m = 0; m < 4; m++)
        af[m] = *(const s16x8*)(smc + (wm * 64 + m * 16 + l15) * 128 + cb);
#pragma unroll
      for (int n = 0; n < 4; n++)
        bfr[n] = *(const s16x8*)(smc + 16384 + (wn * 64 + n * 16 + l15) * 128 + cb);
#pragma unroll
      for (int m = 0; m < 4; m++)
#pragma unroll
        for (int n = 0; n < 4; n++)
          asm volatile("v_mfma_f32_16x16x32_bf16 %0, %1, %2, %0"
                       : "+v"(acc[m][n])
                       : "v"(af[m]), "v"(bfr[n]));
    }
    __syncthreads();
    Ap += 64;
    Bp += 64;
  }
  asm volatile("s_nop 7\n\ts_nop 7\n\ts_nop 7" :::);

  const int gr_base = tm * 128 + wm * 64 + (hi << 2);
  const int gc_base = tn * 128 + wn * 64 + l15;

  int Cc = 0; size_t obase = 0;
  if constexpr (EPI == 3) {
    Cc = (head == 0) ? 9 : ((head == 1) ? 3 : 5);
    obase = (head == 0) ? 0 : ((head == 1) ? (size_t)MROWS * 9 : (size_t)MROWS * 12);
  }

#pragma unroll
  for (int n = 0; n < 4; n++) {
    const int gc = gc_base + n * 16;
    const float bv = bias[gc];
#pragma unroll
    for (int m = 0; m < 4; m++) {
#pragma unroll
      for (int i = 0; i < 4; i++) {
        const int gr = gr_base + m * 16 + i;
        float v = acc[m][n][i] + bv;
        if constexpr (EPI == 0) {
          outb[(size_t)gr * ldo + gc] = f2bf(v);
        } else if constexpr (EPI == 1) {
          int b = gr / PP, p = gr - b * PP;
          float e = bf2f(em[(size_t)gr * DD + gc]) + 0.5f * v;
          ci[(size_t)gr * 1536 + 1024 + gc] =
              (p < nrels[b]) ? f2bf(e) : (unsigned short)0;
        } else if constexpr (EPI == 2) {
          outb[(size_t)gr * ldo + gc] = f2bf(v > 0.f ? v : 0.f);
        } else {
          if (gc < Cc)
            ((float*)outb)[obase + (size_t)gr * Cc + gc] = v;
        }
      }
    }
  }
}

// ---------------- 256x256 8-phase MFMA GEMM (relu+bias epilogue) ----------------
// 8 waves (2M x 4N), per-wave 128x64 output. BK=64, LDS 128 KiB double-buffered.
// Per K-tile: 4 phases (quadrants in Gray order Q00,Q01,Q11,Q10), each phase
// stages one "half-group" of the NEXT tile via global_load_lds. Counted
// vmcnt(4) at phase ends 1,2,4 (FIFO-proven: issue order A0,B0,B1,A1; each
// phase's newly-needed group is >=4 loads old at its wait). Never vmcnt(0).
// LDS groups: A-group a = tile rows with bit6==a, phys rows a*128+[0,128);
// B-group b = cols with bit5==b, phys rows b*128+[0,128). Chunk-XOR swizzle
// via pre-swizzled global source (kg = l7 ^ lr3).
__global__ __launch_bounds__(512, 2) void k_gemm8(
    const unsigned short* __restrict__ A, int ldA,
    const unsigned short* __restrict__ BT, int K,
    int Ntiles, int blocksPerHead,
    long long aHeadOff, long long bHeadOff, long long oHeadOff, int biasHeadOff,
    const float* __restrict__ bias,
    unsigned short* __restrict__ outb, int ldo) {
  __shared__ __align__(16) unsigned short sm[65536];  // 128 KiB
  char* smc = (char*)sm;

  const int swz = swz_xcd(blockIdx.x, gridDim.x);
  const int head = swz / blocksPerHead;
  const int rb = swz - head * blocksPerHead;
  const int tm = rb / Ntiles, tn = rb - (rb / Ntiles) * Ntiles;

  A += (size_t)head * aHeadOff;
  BT += (size_t)head * bHeadOff;
  bias += head * biasHeadOff;
  unsigned short* outp = outb + (size_t)head * oHeadOff;

  const int t = threadIdx.x, l = t & 63, w = t >> 6;
  const int wm = w >> 2, wn = w & 3;
  const int l15 = l & 15, hi = l >> 4, l7 = l & 7, lr3 = l >> 3;
  const int kg = l7 ^ lr3;
  const int u0 = w * 16 + lr3, u1 = u0 + 8;

  int rA0[2], rA1[2], cB0[2], cB1[2];
#pragma unroll
  for (int a = 0; a < 2; a++) {
    rA0[a] = ((u0 >> 6) << 7) + (a << 6) + (u0 & 63);
    rA1[a] = ((u1 >> 6) << 7) + (a << 6) + (u1 & 63);
  }
#pragma unroll
  for (int b = 0; b < 2; b++) {
    cB0[b] = ((u0 >> 5) << 6) + (b << 5) + (u0 & 31);
    cB1[b] = ((u1 >> 5) << 6) + (b << 5) + (u1 & 31);
  }
  const unsigned short* Ag = A + (size_t)(tm * 256) * ldA + kg * 8;
  const unsigned short* Bg = BT + (size_t)(tn * 256) * K + kg * 8;

#define STAGE_A(aC, dstOff, ktof)                                          \
  do {                                                                     \
    gll16(Ag + (size_t)rA0[aC] * ldA + (ktof),                             \
          smc + (dstOff) + (aC) * 16384 + (w * 2 + 0) * 1024);             \
    gll16(Ag + (size_t)rA1[aC] * ldA + (ktof),                             \
          smc + (dstOff) + (aC) * 16384 + (w * 2 + 1) * 1024);             \
  } while (0)
#define STAGE_B(bC, dstOff, ktof)                                          \
  do {                                                                     \
    gll16(Bg + (size_t)cB0[bC] * K + (ktof),                               \
          smc + (dstOff) + 32768 + (bC) * 16384 + (w * 2 + 0) * 1024);     \
    gll16(Bg + (size_t)cB1[bC] * K + (ktof),                               \
          smc + (dstOff) + 32768 + (bC) * 16384 + (w * 2 + 1) * 1024);     \
  } while (0)

  s16x8 af[4][2], bfr[2][2];
  f32x4 acc[8][4] = {};

#define LD_A(aC, bufOff)                                                   \
  do {                                                                     \
    _Pragma("unroll") for (int m_ = 0; m_ < 4; m_++) {                     \
      _Pragma("unroll") for (int k_ = 0; k_ < 2; k_++)                     \
        af[m_][k_] = *(const s16x8*)(smc + (bufOff) + (aC) * 16384 +       \
            (wm * 64 + m_ * 16 + l15) * 128 +                              \
            ((((k_ << 2) + hi) ^ l7) << 4));                               \
    }                                                                      \
  } while (0)
#define LD_B(bC, bufOff)                                                   \
  do {                                                                     \
    _Pragma("unroll") for (int n_ = 0; n_ < 2; n_++) {                     \
      _Pragma("unroll") for (int k_ = 0; k_ < 2; k_++)                     \
        bfr[n_][k_] = *(const s16x8*)(smc + (bufOff) + 32768 +             \
            (bC) * 16384 + (wn * 32 + n_ * 16 + l15) * 128 +               \
            ((((k_ << 2) + hi) ^ l7) << 4));                               \
    }                                                                      \
  } while (0)
#define MFMA_Q(aC, bC)                                                     \
  do {                                                                     \
    _Pragma("unroll") for (int m_ = 0; m_ < 4; m_++) {                     \
      _Pragma("unroll") for (int n_ = 0; n_ < 2; n_++) {                   \
        _Pragma("unroll") for (int k_ = 0; k_ < 2; k_++)                   \
          asm volatile("v_mfma_f32_16x16x32_bf16 %0, %1, %2, %0"           \
                       : "+v"(acc[(aC) * 4 + m_][(bC) * 2 + n_])           \
                       : "v"(af[m_][k_]), "v"(bfr[n_][k_]));               \
      }                                                                    \
    }                                                                      \
  } while (0)
#define PHASE_MID()                                                        \
  __builtin_amdgcn_s_barrier();                                            \
  asm volatile("s_waitcnt lgkmcnt(0)" ::: "memory");                       \
  __builtin_amdgcn_sched_barrier(0);                                       \
  __builtin_amdgcn_s_setprio(1)
#define PHASE_END(VM)                                                      \
  __builtin_amdgcn_s_setprio(0);                                           \
  if (VM) asm volatile("s_waitcnt vmcnt(4)");                              \
  __builtin_amdgcn_s_barrier();                                            \
  asm volatile("" ::: "memory")

  const int NT = K >> 6;
  // prologue: stage tile0 into buf0 (issue order A0,B0,B1,A1)
  STAGE_A(0, 0, 0);
  STAGE_B(0, 0, 0);
  STAGE_B(1, 0, 0);
  STAGE_A(1, 0, 0);
  asm volatile("s_waitcnt vmcnt(4)");
  __builtin_amdgcn_s_barrier();
  asm volatile("" ::: "memory");

  for (int kt = 0; kt < NT; ++kt) {
    const int cur = (kt & 1) << 16;
    const int nxt = cur ^ 65536;
    const int ktof = ((kt + 1 < NT) ? kt + 1 : kt) << 6;  // clamp: dead refetch on last tile

    // phase 1: Q(0,0) ; stage A0(next)
    LD_A(0, cur);
    LD_B(0, cur);
    STAGE_A(0, nxt, ktof);
    PHASE_MID();
    MFMA_Q(0, 0);
    PHASE_END(1);

    // phase 2: Q(0,1) ; stage B0(next)
    LD_B(1, cur);
    STAGE_B(0, nxt, ktof);
    PHASE_MID();
    MFMA_Q(0, 1);
    PHASE_END(1);

    // phase 3: Q(1,1) ; stage B1(next)
    LD_A(1, cur);
    STAGE_B(1, nxt, ktof);
    PHASE_MID();
    MFMA_Q(1, 1);
    PHASE_END(0);

    // phase 4: Q(1,0) ; stage A1(next)
    LD_B(0, cur);
    STAGE_A(1, nxt, ktof);
    PHASE_MID();
    MFMA_Q(1, 0);
    PHASE_END(1);
  }
  asm volatile("s_nop 7\n\ts_nop 7\n\ts_nop 7" :::);

  // epilogue: relu(+bias) -> bf16
  const int gr0 = tm * 256 + wm * 128 + (hi << 2);
  const int gc0 = tn * 256 + wn * 64 + l15;
#pragma unroll
  for (int n = 0; n < 4; n++) {
    const int gc = gc0 + n * 16;
    const float bv = bias[gc];
#pragma unroll
    for (int m = 0; m < 8; m++) {
#pragma unroll
      for (int i = 0; i < 4; i++) {
        const int gr = gr0 + m * 16 + i;
        float v = acc[m][n][i] + bv;
        outp[(size_t)gr * ldo + gc] = f2bf(v > 0.f ? v : 0.f);
      }
    }
  }
#undef STAGE_A
#undef STAGE_B
#undef LD_A
#undef LD_B
#undef MFMA_Q
#undef PHASE_MID
#undef PHASE_END
}

// ---------------- launcher ----------------
extern "C" void kernel_launch(void* const* d_in, const int* in_sizes, int n_in,
                              void* d_out, int out_size, void* d_ws, size_t ws_size,
                              hipStream_t stream) {
  const float* node   = (const float*)d_in[0];
  const float* EF     = (const float*)d_in[1];
  const float* EE     = (const float*)d_in[2];
  const int*   pairs  = (const int*)d_in[3];
  const int*   nrels  = (const int*)d_in[4];
  const float* W_node = (const float*)d_in[5];
  const float* b_node = (const float*)d_in[6];
  const float* W_edge = (const float*)d_in[7];
  const float* b_edge = (const float*)d_in[8];
  const float* hW0[3] = {(const float*)d_in[9],  (const float*)d_in[15], (const float*)d_in[21]};
  const float* hb0[3] = {(const float*)d_in[10], (const float*)d_in[16], (const float*)d_in[22]};
  const float* hW1[3] = {(const float*)d_in[11], (const float*)d_in[17], (const float*)d_in[23]};
  const float* hb1[3] = {(const float*)d_in[12], (const float*)d_in[18], (const float*)d_in[24]};
  const float* hW2[3] = {(const float*)d_in[13], (const float*)d_in[19], (const float*)d_in[25]};
  const float* hb2[3] = {(const float*)d_in[14], (const float*)d_in[20], (const float*)d_in[26]};

  char* ws = (char*)d_ws;
  size_t off = 0;
  auto alloc = [&](size_t bytes) {
    char* p = ws + off;
    off += (bytes + 255) & ~(size_t)255;
    return p;
  };
  unsigned short* WnT   = (unsigned short*)alloc((size_t)512 * 1024 * 2);
  unsigned short* WeT   = (unsigned short*)alloc((size_t)512 * 1024 * 2);
  unsigned short* W0T   = (unsigned short*)alloc((size_t)3072 * 1536 * 2);
  unsigned short* W1T   = (unsigned short*)alloc((size_t)3 * 512 * 1024 * 2);
  unsigned short* W2T   = (unsigned short*)alloc((size_t)3 * 128 * 512 * 2);
  float*          b2pad = (float*)alloc((size_t)3 * 128 * 4);
  float*          b0cat = (float*)alloc((size_t)3072 * 4);
  float*          b1cat = (float*)alloc((size_t)1536 * 4);
  unsigned short* ci    = (unsigned short*)alloc((size_t)MROWS * 1536 * 2);
  unsigned short* h1    = (unsigned short*)alloc((size_t)3 * MROWS * DD * 2);
  // overlay zone: prep buffers, all dead before layer-0 writes h0big on top
  size_t zoneStart = off;
  unsigned short* node_bf = (unsigned short*)alloc((size_t)MNODE * DNF * 2);
  unsigned short* nf      = (unsigned short*)alloc((size_t)MNODE * DD * 2);
  unsigned short* efm     = (unsigned short*)alloc((size_t)MROWS * DEF * 2);
  unsigned short* EMb     = (unsigned short*)alloc((size_t)MROWS * DD * 2);
  size_t zoneEnd = off;

  unsigned short* h0big = (unsigned short*)(ws + zoneStart);
  size_t needFused = zoneStart + (size_t)MROWS * 3072 * 2;
  if (needFused < zoneEnd) needFused = zoneEnd;
  const bool fused = (ws_size >= needFused);
  unsigned short* h0small = efm;  // fallback overlay

  // prep (1 launch): conv + 8 transposes + W2 pad + bias concats
  k_prep<<<11026, 256, 0, stream>>>(node, node_bf, W_node, WnT, W_edge, WeT,
      hW0[0], hW0[1], hW0[2], W0T, hW1[0], hW1[1], hW1[2], W1T,
      hW2[0], hW2[1], hW2[2], hb2[0], hb2[1], hb2[2], W2T, b2pad,
      hb0[0], hb0[1], hb0[2], b0cat, hb1[0], hb1[1], hb1[2], b1cat);
  k_gather_ef<<<MROWS, 256, 0, stream>>>(EF, EE, pairs, efm, EMb);

  // nf = node_bf @ WnT^T + b_node  (M=3072,N=512,K=1024)
  k_gemm<0><<<(MNODE / 128) * 4, 256, 0, stream>>>(
      node_bf, WnT, 4, 1024, b_node, nf, 512, nullptr, nullptr, nullptr);
  k_gather_ci<<<MROWS, 256, 0, stream>>>(nf, pairs, nrels, ci);
  // ci[:,1024:1536] = 0.25*(ee+ee') + 0.5*(efm@We + b_edge), masked
  k_gemm<1><<<MTILES * 4, 256, 0, stream>>>(
      efm, WeT, 4, 1024, b_edge, nullptr, 0, EMb, nrels, ci);

  if (fused) {
    // layer0 fused over heads: [16896,1536] x [3072,1536]^T -> h0big [16896,3072]
    k_gemm8<<<(MROWS / 256) * 12, 512, 0, stream>>>(
        ci, 1536, W0T, 1536, 12, (MROWS / 256) * 12,
        0, 0, 0, 0, b0cat, h0big, 3072);
    // layer1 fused: per head [16896,1024] x [512,1024]^T -> h1[h]
    k_gemm8<<<3 * (MROWS / 256) * 2, 512, 0, stream>>>(
        h0big, 3072, W1T, 1024, 2, (MROWS / 256) * 2,
        1024, (long long)512 * 1024, (long long)MROWS * DD, 512, b1cat, h1, 512);
  } else {
    for (int h = 0; h < 3; h++) {
      k_gemm<2><<<MTILES * 8, 256, 0, stream>>>(
          ci, W0T + (size_t)h * 1024 * 1536, 8, 1536, hb0[h],
          h0small, 1024, nullptr, nullptr, nullptr);
      k_gemm<2><<<MTILES * 4, 256, 0, stream>>>(
          h0small, W1T + (size_t)h * 512 * 1024, 4, 1024, hb1[h],
          h1 + (size_t)h * MROWS * DD, 512, nullptr, nullptr, nullptr);
    }
  }

  // layer2: merged padded GEMM -> d_out (fp32) lr | cr | mr
  k_gemm<3><<<3 * MTILES, 256, 0, stream>>>(
      h1, W2T, 1, 512, b2pad, (unsigned short*)d_out, 0,
      nullptr, nullptr, nullptr);
}

// Round 4
// 388.996 us; speedup vs baseline: 1.5536x; 1.0158x over previous
//
#include <hip/hip_runtime.h>
#include <stdint.h>

// Problem constants
#define BB 256
#define NNODE 12
#define PP 66
#define DNF 1024
#define DEF 1024
#define DD 512
#define MROWS (BB*PP)        // 16896
#define MNODE (BB*NNODE)     // 3072
#define MTILES (MROWS/128)   // 132

typedef __attribute__((ext_vector_type(8))) short s16x8;
typedef __attribute__((ext_vector_type(4))) float f32x4;

__device__ __forceinline__ unsigned short f2bf(float f) {
  union { float f; unsigned u; } v; v.f = f;
  return (unsigned short)((v.u + 0x7FFFu + ((v.u >> 16) & 1u)) >> 16);
}
__device__ __forceinline__ float bf2f(unsigned short h) {
  union { unsigned u; float f; } v; v.u = ((unsigned)h) << 16;
  return v.f;
}

__device__ __forceinline__ void gll16(const void* g, void* l) {
  __builtin_amdgcn_global_load_lds(
      (const __attribute__((address_space(1))) void*)g,
      (__attribute__((address_space(3))) void*)l, 16, 0, 0);
}

// bijective XCD-chunk swizzle (m204)
__device__ __forceinline__ int swz_xcd(int orig, int nwg) {
  int q = nwg >> 3, r = nwg & 7, x = orig & 7;
  return (x < r ? x * (q + 1) : r * (q + 1) + (x - r) * q) + (orig >> 3);
}

// ---------------- fused prep kernel ----------------
__global__ __launch_bounds__(256) void k_prep(
    const float* __restrict__ node, unsigned short* __restrict__ node_bf,
    const float* __restrict__ W_node, unsigned short* __restrict__ WnT,
    const float* __restrict__ W_edge, unsigned short* __restrict__ WeT,
    const float* __restrict__ W0a, const float* __restrict__ W0b,
    const float* __restrict__ W0c, unsigned short* __restrict__ W0T,
    const float* __restrict__ W1a, const float* __restrict__ W1b,
    const float* __restrict__ W1c, unsigned short* __restrict__ W1T,
    const float* __restrict__ w2a, const float* __restrict__ w2b,
    const float* __restrict__ w2c,
    const float* __restrict__ b2a, const float* __restrict__ b2b,
    const float* __restrict__ b2c,
    unsigned short* __restrict__ W2T, float* __restrict__ b2pad,
    const float* __restrict__ b0a, const float* __restrict__ b0b,
    const float* __restrict__ b0c, float* __restrict__ b0cat,
    const float* __restrict__ b1a, const float* __restrict__ b1b,
    const float* __restrict__ b1c, float* __restrict__ b1cat) {
  __shared__ float tile[32][33];
  const int bid = blockIdx.x, t = threadIdx.x;
  if (bid < 3072) {
    int i = bid * 256 + t;
    float4 v = ((const float4*)node)[i];
    ushort4 o;
    o.x = f2bf(v.x); o.y = f2bf(v.y); o.z = f2bf(v.z); o.w = f2bf(v.w);
    ((ushort4*)node_bf)[i] = o;
  } else if (bid < 10240) {
    int tau = bid - 3072;
    const float* src; unsigned short* dst; int K, N;
    if (tau < 512)       { src = W_node; dst = WnT; K = 1024; N = 512; }
    else if (tau < 1024) { src = W_edge; dst = WeT; K = 1024; N = 512; tau -= 512; }
    else if (tau < 5632) {
      int hh = (tau - 1024) / 1536; tau = (tau - 1024) % 1536;
      src = hh == 0 ? W0a : (hh == 1 ? W0b : W0c);
      dst = W0T + (size_t)hh * 1024 * 1536; K = 1536; N = 1024;
    } else {
      int hh = (tau - 5632) / 512; tau = (tau - 5632) % 512;
      src = hh == 0 ? W1a : (hh == 1 ? W1b : W1c);
      dst = W1T + (size_t)hh * 512 * 1024; K = 1024; N = 512;
    }
    int ntiles = N >> 5;
    int kb = (tau / ntiles) * 32, nb = (tau % ntiles) * 32;
    int tx = t & 31, ty = t >> 5;
#pragma unroll
    for (int i = 0; i < 32; i += 8)
      tile[ty + i][tx] = src[(size_t)(kb + ty + i) * N + nb + tx];
    __syncthreads();
#pragma unroll
    for (int i = 0; i < 32; i += 8)
      dst[(size_t)(nb + ty + i) * K + kb + tx] = f2bf(tile[tx][ty + i]);
  } else if (bid < 11008) {
    int e = bid - 10240;
    int h = e >> 8, blk = e & 255;
    const int C = (h == 0) ? 9 : ((h == 1) ? 3 : 5);
    const float* W2 = (h == 0) ? w2a : ((h == 1) ? w2b : w2c);
    const float* b2 = (h == 0) ? b2a : ((h == 1) ? b2b : b2c);
    int idx = blk * 256 + t;
    int n = idx >> 9, k = idx & 511;
    W2T[(size_t)h * 65536 + idx] = (n < C) ? f2bf(W2[(size_t)k * C + n]) : (unsigned short)0;
    if (blk == 0 && t < 128)
      b2pad[h * 128 + t] = (t < C) ? b2[t] : 0.f;
  } else if (bid < 11020) {
    int j = bid - 11008;
    const float* b0 = (j < 4) ? b0a : (j < 8 ? b0b : b0c);
    b0cat[j * 256 + t] = b0[(j & 3) * 256 + t];
  } else {
    int j = bid - 11020;
    const float* b1 = (j < 2) ? b1a : (j < 4 ? b1b : b1c);
    b1cat[j * 256 + t] = b1[(j & 1) * 256 + t];
  }
}

// ---------------- gathers ----------------
__global__ __launch_bounds__(256) void k_gather_ef(const float* __restrict__ EF,
                                                   const float* __restrict__ EE,
                                                   const int* __restrict__ pairs,
                                                   unsigned short* __restrict__ efm,
                                                   unsigned short* __restrict__ emb) {
  int r = blockIdx.x;
  int b = r / PP;
  int i0 = pairs[r * 2 + 0], i1 = pairs[r * 2 + 1];
  int t = threadIdx.x;
  const float4* e01 = (const float4*)(EF + ((size_t)((b * NNODE + i0) * NNODE + i1)) * DEF);
  const float4* e10 = (const float4*)(EF + ((size_t)((b * NNODE + i1) * NNODE + i0)) * DEF);
  float4 a = e01[t], c = e10[t];
  ushort4 o;
  o.x = f2bf(0.5f * (a.x + c.x));
  o.y = f2bf(0.5f * (a.y + c.y));
  o.z = f2bf(0.5f * (a.z + c.z));
  o.w = f2bf(0.5f * (a.w + c.w));
  ((ushort4*)(efm + (size_t)r * DEF))[t] = o;
  const float2* g01 = (const float2*)(EE + ((size_t)((b * NNODE + i0) * NNODE + i1)) * DD);
  const float2* g10 = (const float2*)(EE + ((size_t)((b * NNODE + i1) * NNODE + i0)) * DD);
  float2 x = g01[t], y = g10[t];
  ushort2 eo;
  eo.x = f2bf(0.25f * (x.x + y.x));
  eo.y = f2bf(0.25f * (x.y + y.y));
  ((ushort2*)(emb + (size_t)r * DD))[t] = eo;
}

__global__ __launch_bounds__(256) void k_gather_ci(const unsigned short* __restrict__ nf,
                                                   const int* __restrict__ pairs,
                                                   const int* __restrict__ nrels,
                                                   unsigned short* __restrict__ ci) {
  int r = blockIdx.x;
  int b = r / PP, p = r - b * PP;
  bool valid = p < nrels[b];
  int i0 = pairs[r * 2 + 0], i1 = pairs[r * 2 + 1];
  int t = threadIdx.x;
  int col = t * 4;
  ushort4 v = make_ushort4(0, 0, 0, 0);
  if (valid) {
    const unsigned short* src = (col < 512)
        ? nf + ((size_t)(b * NNODE + i0)) * DD + col
        : nf + ((size_t)(b * NNODE + i1)) * DD + (col - 512);
    v = *(const ushort4*)src;
  }
  ((ushort4*)(ci + (size_t)r * 1536))[t] = v;
}

// ---------------- 128-tile MFMA GEMM (small shapes + fallback) ----------------
template <int EPI>
__global__ __launch_bounds__(256) void k_gemm(
    const unsigned short* __restrict__ A,
    const unsigned short* __restrict__ BT,
    int Ntiles, int K,
    const float* __restrict__ bias,
    unsigned short* __restrict__ outb, int ldo,
    const unsigned short* __restrict__ em,
    const int* __restrict__ nrels,
    unsigned short* __restrict__ ci) {
  __shared__ __align__(16) unsigned short sm[16384];
  char* smc = (char*)sm;
  const int t = threadIdx.x;
  const int l = t & 63, w = t >> 6;
  const int wm = w >> 1, wn = w & 1;
  const int bid = blockIdx.x;
  int tn = bid % Ntiles, tm = bid / Ntiles;

  int head = 0;
  if constexpr (EPI == 3) {
    head = tm / MTILES;
    tm = tm - head * MTILES;
    A += (size_t)head * MROWS * DD;
    BT += (size_t)head * 128 * DD;
    bias += head * 128;
  }

  const int lrow = l >> 3;
  const int scol = (l & 7) ^ lrow;
  const unsigned short* Ap = A + (size_t)(tm * 128 + w * 8 + lrow) * K + scol * 8;
  const unsigned short* Bp = BT + (size_t)(tn * 128 + w * 8 + lrow) * K + scol * 8;

  f32x4 acc[4][4] = {};
  const int hi = l >> 4, l15 = l & 15, l7 = l & 7;
  const int nk = K >> 6;

  for (int kt = 0; kt < nk; ++kt) {
#pragma unroll
    for (int c = 0; c < 4; ++c) {
      gll16(Ap + (size_t)c * 32 * K, smc + c * 4096 + w * 1024);
      gll16(Bp + (size_t)c * 32 * K, smc + 16384 + c * 4096 + w * 1024);
    }
    __syncthreads();
#pragma unroll
    for (int kk = 0; kk < 2; ++kk) {
      const int cb = (((kk << 2) + hi) ^ l7) << 4;
      s16x8 af[4], bfr[4];
#pragma unroll
      for (int m = 0; m < 4; m++)
        af[m] = *(const s16x8*)(smc + (wm * 64 + m * 16 + l15) * 128 + cb);
#pragma unroll
      for (int n = 0; n < 4; n++)
        bfr[n] = *(const s16x8*)(smc + 16384 + (wn * 64 + n * 16 + l15) * 128 + cb);
#pragma unroll
      for (int m = 0; m < 4; m++)
#pragma unroll
        for (int n = 0; n < 4; n++)
          asm volatile("v_mfma_f32_16x16x32_bf16 %0, %1, %2, %0"
                       : "+v"(acc[m][n])
                       : "v"(af[m]), "v"(bfr[n]));
    }
    __syncthreads();
    Ap += 64;
    Bp += 64;
  }
  asm volatile("s_nop 7\n\ts_nop 7\n\ts_nop 7" :::);

  const int gr_base = tm * 128 + wm * 64 + (hi << 2);
  const int gc_base = tn * 128 + wn * 64 + l15;

  int Cc = 0; size_t obase = 0;
  if constexpr (EPI == 3) {
    Cc = (head == 0) ? 9 : ((head == 1) ? 3 : 5);
    obase = (head == 0) ? 0 : ((head == 1) ? (size_t)MROWS * 9 : (size_t)MROWS * 12);
  }

#pragma unroll
  for (int n = 0; n < 4; n++) {
    const int gc = gc_base + n * 16;
    const float bv = bias[gc];
#pragma unroll
    for (int m = 0; m < 4; m++) {
#pragma unroll
      for (int i = 0; i < 4; i++) {
        const int gr = gr_base + m * 16 + i;
        float v = acc[m][n][i] + bv;
        if constexpr (EPI == 0) {
          outb[(size_t)gr * ldo + gc] = f2bf(v);
        } else if constexpr (EPI == 1) {
          int b = gr / PP, p = gr - b * PP;
          float e = bf2f(em[(size_t)gr * DD + gc]) + 0.5f * v;
          ci[(size_t)gr * 1536 + 1024 + gc] =
              (p < nrels[b]) ? f2bf(e) : (unsigned short)0;
        } else if constexpr (EPI == 2) {
          outb[(size_t)gr * ldo + gc] = f2bf(v > 0.f ? v : 0.f);
        } else {
          if (gc < Cc)
            ((float*)outb)[obase + (size_t)gr * Cc + gc] = v;
        }
      }
    }
  }
}

// ---------------- 256x128 3-buffer depth-2 MFMA GEMM (relu+bias) ----------------
// 8 waves (4M x 2N), per-wave 64x64 output. BK=64. LDS = 3 bufs x (A 32K + B 16K).
// Per K-tile: ONE barrier + ONE counted vmcnt(12); tile t+2 staged at top of
// tile t (depth-2 prefetch, 2 K-tiles of slack); compute free-runs with no
// intra-tile barriers so waves stagger and LDS-pipe overlaps MFMA-pipe.
// Race-proof: barrier separates "all waves done reading buf[(t+2)%3] (=tile
// t-1)" from stage-writes into it; vmcnt(12) (= t+1's 6 + t+2's 6 in flight)
// guarantees tile t resident; load counts uniform (clamped dead re-stage at
// the tail) so the accounting is exact. Chunk-XOR LDS swizzle via
// pre-swizzled global source (kg = l7 ^ (l>>3)); ds_read side applies the
// same XOR -> measured 0 bank conflicts in this family.
__global__ __launch_bounds__(512, 1) void k_gemm3(
    const unsigned short* __restrict__ A, int ldA,
    const unsigned short* __restrict__ BT, int K,
    int Ntiles, int blocksPerHead,
    long long aHeadOff, long long bHeadOff, long long oHeadOff, int biasHeadOff,
    const float* __restrict__ bias,
    unsigned short* __restrict__ outb, int ldo) {
  __shared__ __align__(16) unsigned short sm[73728];  // 144 KiB
  char* smc = (char*)sm;

  const int swz = swz_xcd(blockIdx.x, gridDim.x);
  const int head = swz / blocksPerHead;
  const int rb = swz - head * blocksPerHead;
  const int tm = rb / Ntiles, tn = rb - (rb / Ntiles) * Ntiles;

  A += (size_t)head * aHeadOff;
  BT += (size_t)head * bHeadOff;
  bias += head * biasHeadOff;
  unsigned short* outp = outb + (size_t)head * oHeadOff;

  const int t = threadIdx.x, l = t & 63, w = t >> 6;
  const int wm = w >> 1, wn = w & 1;
  const int l15 = l & 15, hi = l >> 4, l7 = l & 7, lr3 = l >> 3;
  const int kg = l7 ^ lr3;  // pre-swizzled source chunk

  // per-lane row pointers for staging (4 A-rows, 2 B-rows per thread)
  const unsigned short* rAp[4];
  const unsigned short* rBp[2];
#pragma unroll
  for (int i = 0; i < 4; i++)
    rAp[i] = A + (size_t)(tm * 256 + i * 64 + w * 8 + lr3) * ldA + kg * 8;
#pragma unroll
  for (int i = 0; i < 2; i++)
    rBp[i] = BT + (size_t)(tn * 128 + i * 64 + w * 8 + lr3) * K + kg * 8;

#define STAGE(ktof, sbOff)                                                 \
  do {                                                                     \
    _Pragma("unroll") for (int i_ = 0; i_ < 4; i_++)                       \
      gll16(rAp[i_] + ((ktof) << 6), smc + (sbOff) + i_ * 8192 + w * 1024);\
    _Pragma("unroll") for (int i_ = 0; i_ < 2; i_++)                       \
      gll16(rBp[i_] + ((ktof) << 6),                                       \
            smc + (sbOff) + 32768 + i_ * 8192 + w * 1024);                 \
  } while (0)

  f32x4 acc[4][4] = {};
  const int NT = K >> 6;

  // prologue: stage tiles 0,1 into bufs 0,1 (6 loads/thread each)
  STAGE(0, 0);
  STAGE(1, 49152);

  int sb = 2 * 49152;  // stage buffer byte offset (cycles 2,0,1,...)
  int cbuf = 0;        // compute buffer byte offset
  for (int kt = 0; kt < NT; ++kt) {
    const int ktof = (kt + 2 < NT) ? kt + 2 : NT - 1;  // clamped (dead tail re-stage)
    __syncthreads();            // all waves done reading buf sb (held tile kt-1)
    STAGE(ktof, sb);            // issue tile kt+2 (6 loads/thread)
    asm volatile("s_waitcnt vmcnt(12)" ::: "memory");  // tile kt resident; 12 in flight

#pragma unroll
    for (int kk = 0; kk < 2; ++kk) {
      const int cb0 = (((kk << 2) + hi) ^ l7) << 4;
      s16x8 af[4], bfv[4];
#pragma unroll
      for (int m = 0; m < 4; m++)
        af[m] = *(const s16x8*)(smc + cbuf + (wm * 64 + m * 16 + l15) * 128 + cb0);
#pragma unroll
      for (int n = 0; n < 4; n++)
        bfv[n] = *(const s16x8*)(smc + cbuf + 32768 + (wn * 64 + n * 16 + l15) * 128 + cb0);
      __builtin_amdgcn_s_setprio(1);
#pragma unroll
      for (int m = 0; m < 4; m++)
#pragma unroll
        for (int n = 0; n < 4; n++)
          asm volatile("v_mfma_f32_16x16x32_bf16 %0, %1, %2, %0"
                       : "+v"(acc[m][n])
                       : "v"(af[m]), "v"(bfv[n]));
      __builtin_amdgcn_s_setprio(0);
    }
    // rotate buffers: cbuf -> cbuf+1 (mod 3), sb -> old cbuf
    sb = cbuf;
    cbuf = (cbuf == 2 * 49152) ? 0 : cbuf + 49152;
  }
  asm volatile("s_nop 7\n\ts_nop 7\n\ts_nop 7" :::);  // MFMA->VALU hazard guard

  // epilogue: relu(+bias) -> bf16
  const int gr0 = tm * 256 + wm * 64 + (hi << 2);
  const int gc0 = tn * 128 + wn * 64 + l15;
#pragma unroll
  for (int n = 0; n < 4; n++) {
    const int gc = gc0 + n * 16;
    const float bv = bias[gc];
#pragma unroll
    for (int m = 0; m < 4; m++) {
#pragma unroll
      for (int i = 0; i < 4; i++) {
        const int gr = gr0 + m * 16 + i;
        float v = acc[m][n][i] + bv;
        outp[(size_t)gr * ldo + gc] = f2bf(v > 0.f ? v : 0.f);
      }
    }
  }
#undef STAGE
}

// ---------------- launcher ----------------
extern "C" void kernel_launch(void* const* d_in, const int* in_sizes, int n_in,
                              void* d_out, int out_size, void* d_ws, size_t ws_size,
                              hipStream_t stream) {
  const float* node   = (const float*)d_in[0];
  const float* EF     = (const float*)d_in[1];
  const float* EE     = (const float*)d_in[2];
  const int*   pairs  = (const int*)d_in[3];
  const int*   nrels  = (const int*)d_in[4];
  const float* W_node = (const float*)d_in[5];
  const float* b_node = (const float*)d_in[6];
  const float* W_edge = (const float*)d_in[7];
  const float* b_edge = (const float*)d_in[8];
  const float* hW0[3] = {(const float*)d_in[9],  (const float*)d_in[15], (const float*)d_in[21]};
  const float* hb0[3] = {(const float*)d_in[10], (const float*)d_in[16], (const float*)d_in[22]};
  const float* hW1[3] = {(const float*)d_in[11], (const float*)d_in[17], (const float*)d_in[23]};
  const float* hb1[3] = {(const float*)d_in[12], (const float*)d_in[18], (const float*)d_in[24]};
  const float* hW2[3] = {(const float*)d_in[13], (const float*)d_in[19], (const float*)d_in[25]};
  const float* hb2[3] = {(const float*)d_in[14], (const float*)d_in[20], (const float*)d_in[26]};

  char* ws = (char*)d_ws;
  size_t off = 0;
  auto alloc = [&](size_t bytes) {
    char* p = ws + off;
    off += (bytes + 255) & ~(size_t)255;
    return p;
  };
  unsigned short* WnT   = (unsigned short*)alloc((size_t)512 * 1024 * 2);
  unsigned short* WeT   = (unsigned short*)alloc((size_t)512 * 1024 * 2);
  unsigned short* W0T   = (unsigned short*)alloc((size_t)3072 * 1536 * 2);
  unsigned short* W1T   = (unsigned short*)alloc((size_t)3 * 512 * 1024 * 2);
  unsigned short* W2T   = (unsigned short*)alloc((size_t)3 * 128 * 512 * 2);
  float*          b2pad = (float*)alloc((size_t)3 * 128 * 4);
  float*          b0cat = (float*)alloc((size_t)3072 * 4);
  float*          b1cat = (float*)alloc((size_t)1536 * 4);
  unsigned short* ci    = (unsigned short*)alloc((size_t)MROWS * 1536 * 2);
  unsigned short* h1    = (unsigned short*)alloc((size_t)3 * MROWS * DD * 2);
  // overlay zone: prep buffers, all dead before layer-0 writes h0big on top
  size_t zoneStart = off;
  unsigned short* node_bf = (unsigned short*)alloc((size_t)MNODE * DNF * 2);
  unsigned short* nf      = (unsigned short*)alloc((size_t)MNODE * DD * 2);
  unsigned short* efm     = (unsigned short*)alloc((size_t)MROWS * DEF * 2);
  unsigned short* EMb     = (unsigned short*)alloc((size_t)MROWS * DD * 2);
  size_t zoneEnd = off;

  unsigned short* h0big = (unsigned short*)(ws + zoneStart);
  size_t needFused = zoneStart + (size_t)MROWS * 3072 * 2;
  if (needFused < zoneEnd) needFused = zoneEnd;
  const bool fused = (ws_size >= needFused);
  unsigned short* h0small = efm;  // fallback overlay

  // prep (1 launch)
  k_prep<<<11026, 256, 0, stream>>>(node, node_bf, W_node, WnT, W_edge, WeT,
      hW0[0], hW0[1], hW0[2], W0T, hW1[0], hW1[1], hW1[2], W1T,
      hW2[0], hW2[1], hW2[2], hb2[0], hb2[1], hb2[2], W2T, b2pad,
      hb0[0], hb0[1], hb0[2], b0cat, hb1[0], hb1[1], hb1[2], b1cat);
  k_gather_ef<<<MROWS, 256, 0, stream>>>(EF, EE, pairs, efm, EMb);

  // nf = node_bf @ WnT^T + b_node  (M=3072,N=512,K=1024)
  k_gemm<0><<<(MNODE / 128) * 4, 256, 0, stream>>>(
      node_bf, WnT, 4, 1024, b_node, nf, 512, nullptr, nullptr, nullptr);
  k_gather_ci<<<MROWS, 256, 0, stream>>>(nf, pairs, nrels, ci);
  // ci[:,1024:1536] = 0.25*(ee+ee') + 0.5*(efm@We + b_edge), masked
  k_gemm<1><<<MTILES * 4, 256, 0, stream>>>(
      efm, WeT, 4, 1024, b_edge, nullptr, 0, EMb, nrels, ci);

  if (fused) {
    // layer0 fused over heads: [16896,1536] x [3072,1536]^T -> h0big [16896,3072]
    k_gemm3<<<(MROWS / 256) * 24, 512, 0, stream>>>(
        ci, 1536, W0T, 1536, 24, (MROWS / 256) * 24,
        0, 0, 0, 0, b0cat, h0big, 3072);
    // layer1: per head [16896,1024] x [512,1024]^T -> h1[h]
    k_gemm3<<<3 * (MROWS / 256) * 4, 512, 0, stream>>>(
        h0big, 3072, W1T, 1024, 4, (MROWS / 256) * 4,
        1024, (long long)512 * 1024, (long long)MROWS * DD, 512, b1cat, h1, 512);
  } else {
    for (int h = 0; h < 3; h++) {
      k_gemm<2><<<MTILES * 8, 256, 0, stream>>>(
          ci, W0T + (size_t)h * 1024 * 1536, 8, 1536, hb0[h],
          h0small, 1024, nullptr, nullptr, nullptr);
      k_gemm<2><<<MTILES * 4, 256, 0, stream>>>(
          h0small, W1T + (size_t)h * 512 * 1024, 4, 1024, hb1[h],
          h1 + (size_t)h * MROWS * DD, 512, nullptr, nullptr, nullptr);
    }
  }

  // layer2: merged padded GEMM -> d_out (fp32) lr | cr | mr
  k_gemm<3><<<3 * MTILES, 256, 0, stream>>>(
      h1, W2T, 1, 512, b2pad, (unsigned short*)d_out, 0,
      nullptr, nullptr, nullptr);
}